// Round 1
// baseline (4350.655 us; speedup 1.0000x reference)
//
#include <hip/hip_runtime.h>
#include <math.h>

#define Bdim 2
#define Tdim 1024
#define Cdim 1024
#define Hdim 16
#define Ndim 64
#define EPS_GN 0.00064f

static __device__ __forceinline__ float sigf(float x) { return 1.f / (1.f + expf(-x)); }

static __device__ __forceinline__ float wsum64(float v) {
    #pragma unroll
    for (int m = 1; m < 64; m <<= 1) v += __shfl_xor(v, m);
    return v;
}

// ---------------------------------------------------------------------------
// Big GEMM: out[m][n] = sum_k A[m][k] * W[n][k]   (W used transposed)
// Optional fused token-shift lerp on A: A[m][k] = x[m][k] + (x[m-1][k] - x[m][k])*mix[k]
// BM=128, BN=64, BK=16, 256 threads, 8x4 per thread.
// ---------------------------------------------------------------------------
#define BM 128
#define BN 64
#define BK 16

__global__ __launch_bounds__(256) void gemm_btk(
    const float* __restrict__ Asrc, const float* __restrict__ mixv,
    const float* __restrict__ W, float* __restrict__ Cout,
    int M, int N, int K, int Tlen, int lerp)
{
    __shared__ float As[BK][BM];
    __shared__ float Ws[BK][BN];
    int tid = threadIdx.x;
    int bm = blockIdx.y * BM, bn = blockIdx.x * BN;
    int tx = tid & 15, ty = tid >> 4;
    float acc[8][4];
    #pragma unroll
    for (int i = 0; i < 8; ++i)
        #pragma unroll
        for (int j = 0; j < 4; ++j) acc[i][j] = 0.f;

    int lrA = tid >> 1;          // 0..127
    int lkA = (tid & 1) * 8;     // 0 or 8
    int lrW = tid >> 2;          // 0..63
    int lkW = (tid & 3) * 4;     // 0,4,8,12

    for (int k0 = 0; k0 < K; k0 += BK) {
        {   // A tile (optionally lerped)
            int m = bm + lrA;
            const float* p = Asrc + (size_t)m * K + k0 + lkA;
            #pragma unroll
            for (int q = 0; q < 2; ++q) {
                float4 v = *(const float4*)(p + q * 4);
                if (lerp) {
                    int t = m % Tlen;
                    float4 pv = make_float4(0.f, 0.f, 0.f, 0.f);
                    if (t > 0) pv = *(const float4*)(p + q * 4 - K);
                    float4 mv = *(const float4*)(mixv + k0 + lkA + q * 4);
                    v.x += (pv.x - v.x) * mv.x;
                    v.y += (pv.y - v.y) * mv.y;
                    v.z += (pv.z - v.z) * mv.z;
                    v.w += (pv.w - v.w) * mv.w;
                }
                As[lkA + q * 4 + 0][lrA] = v.x;
                As[lkA + q * 4 + 1][lrA] = v.y;
                As[lkA + q * 4 + 2][lrA] = v.z;
                As[lkA + q * 4 + 3][lrA] = v.w;
            }
        }
        {   // W tile
            int n = bn + lrW;
            const float* p = W + (size_t)n * K + k0 + lkW;
            float4 v = *(const float4*)p;
            Ws[lkW + 0][lrW] = v.x; Ws[lkW + 1][lrW] = v.y;
            Ws[lkW + 2][lrW] = v.z; Ws[lkW + 3][lrW] = v.w;
        }
        __syncthreads();
        #pragma unroll
        for (int kk = 0; kk < BK; ++kk) {
            float a8[8], w4[4];
            *(float4*)&a8[0] = *(const float4*)&As[kk][ty * 8];
            *(float4*)&a8[4] = *(const float4*)&As[kk][ty * 8 + 4];
            *(float4*)&w4[0] = *(const float4*)&Ws[kk][tx * 4];
            #pragma unroll
            for (int i = 0; i < 8; ++i)
                #pragma unroll
                for (int j = 0; j < 4; ++j)
                    acc[i][j] += a8[i] * w4[j];
        }
        __syncthreads();
    }
    #pragma unroll
    for (int i = 0; i < 8; ++i) {
        int m = bm + ty * 8 + i;
        #pragma unroll
        for (int j = 0; j < 4; ++j)
            Cout[(size_t)m * N + bn + tx * 4 + j] = acc[i][j];
    }
}

// ---------------------------------------------------------------------------
// Low-rank stage 1: H[m][n] = act( sum_k lerp(x)[m][k] * M1[k][n] ), n < D
// One row per block, 256 threads, K split 256/D ways, LDS reduce.
// act: 0 none, 1 sigmoid, 2 tanh
// ---------------------------------------------------------------------------
__global__ __launch_bounds__(256) void lr1_kernel(
    const float* __restrict__ X, const float* __restrict__ mixv,
    const float* __restrict__ M1, float* __restrict__ Hout,
    int D, int act, int Tlen)
{
    __shared__ float row[Cdim];
    __shared__ float red[256];
    int m = blockIdx.x;
    int tid = threadIdx.x;
    int t = m % Tlen;
    const float* xr = X + (size_t)m * Cdim;
    #pragma unroll
    for (int q = 0; q < 4; ++q) {
        int kq = tid + q * 256;
        float v = xr[kq];
        float pv = (t > 0) ? xr[kq - Cdim] : 0.f;
        row[kq] = v + (pv - v) * mixv[kq];
    }
    __syncthreads();
    int P = 256 / D;
    int p = tid / D, n = tid % D;
    int klen = Cdim / P;
    float acc = 0.f;
    int kend = (p + 1) * klen;
    for (int k = p * klen; k < kend; ++k)
        acc += row[k] * M1[(size_t)k * D + n];
    red[tid] = acc;
    __syncthreads();
    if (tid < D) {
        float s = 0.f;
        for (int q = 0; q < P; ++q) s += red[tid + q * D];
        if (act == 1) s = sigf(s);
        else if (act == 2) s = tanhf(s);
        Hout[(size_t)m * D + tid] = s;
    }
}

// ---------------------------------------------------------------------------
// Low-rank stage 2: Out[m][n] = act( sum_k H[m][k]*M2[k][n] + bias[n] )
// act: 0 none, 1 sigmoid, 3 sigmoid * e^-0.5   (decay = exp(-softplus(-dt)-0.5))
// grid (N/256, M)
// ---------------------------------------------------------------------------
__global__ __launch_bounds__(256) void lr2_kernel(
    const float* __restrict__ Hin, const float* __restrict__ M2,
    const float* __restrict__ bias, float* __restrict__ Out,
    int D, int act)
{
    __shared__ float hs[128];
    int m = blockIdx.y;
    int n = blockIdx.x * 256 + threadIdx.x;
    if (threadIdx.x < D) hs[threadIdx.x] = Hin[(size_t)m * D + threadIdx.x];
    __syncthreads();
    float acc = bias ? bias[n] : 0.f;
    for (int k = 0; k < D; ++k)
        acc += hs[k] * M2[(size_t)k * Cdim + n];
    if (act == 1) acc = sigf(acc);
    else if (act == 3) acc = sigf(acc) * 0.60653065971263342f;
    Out[(size_t)m * Cdim + n] = acc;
}

// ---------------------------------------------------------------------------
// E1: per (b,t,h) group of 64: kk-normalize -> a=-kkn, b=kkn*at;
//     ut = (sum rt*k*r_k)*vmix; out2 = v_first copy.
// 256 threads = 4 waves, one group per wave.
// ---------------------------------------------------------------------------
__global__ __launch_bounds__(256) void e1_kernel(
    const float* __restrict__ kt, const float* __restrict__ at,
    const float* __restrict__ rt, const float* __restrict__ vraw,
    const float* __restrict__ vt, const float* __restrict__ vfirst,
    const float* __restrict__ k_k, const float* __restrict__ k_a,
    const float* __restrict__ r_k,
    float* __restrict__ aarr, float* __restrict__ barr,
    float* __restrict__ ut, float* __restrict__ out2)
{
    int gid = blockIdx.x * 4 + (threadIdx.x >> 6);
    int lane = threadIdx.x & 63;
    int h = gid % Hdim;
    size_t idx = (size_t)gid * 64 + lane;
    int c = h * 64 + lane;
    float ktv = kt[idx], atv = at[idx];
    float kk = ktv * k_k[c];
    float ss = wsum64(kk * kk);
    float norm = sqrtf(ss);
    float kkn = kk / fmaxf(norm, 1e-12f);
    aarr[idx] = -kkn;
    barr[idx] = kkn * atv;
    float kmix = ktv * (1.f + (atv - 1.f) * k_a[c]);
    float rv = rt[idx];
    float dot = wsum64(rv * kmix * r_k[c]);
    float vm = vraw[idx];
    float vf = vfirst[idx];
    vm = vm + (vf - vm) * vt[idx];
    ut[idx] = dot * vm;
    out2[idx] = vf;
}

// ---------------------------------------------------------------------------
// WKV scan: one wave per (b,h). Lane i holds state row S[i][0..63] in regs.
// S[i][j] = S[i][j]*d[j] + (S[i][:].a)*b[j] + v[i]*k[j];  out[i] = S[i][:].r
// j-indexed operands are wave-uniform float4 loads (scalarizable -> s_load).
// ---------------------------------------------------------------------------
__global__ __launch_bounds__(64) void wkv_kernel(
    const float* __restrict__ rt, const float* __restrict__ decay,
    const float* __restrict__ kt, const float* __restrict__ vt,
    const float* __restrict__ aarr, const float* __restrict__ barr,
    float* __restrict__ wkvt)
{
    int bh = blockIdx.x;
    int b = bh / Hdim, h = bh % Hdim;
    int lane = threadIdx.x;
    float S[64];
    #pragma unroll
    for (int j = 0; j < 64; ++j) S[j] = 0.f;
    size_t base = ((size_t)b * Tdim) * Cdim + (size_t)h * Ndim;
    for (int t = 0; t < Tdim; ++t, base += Cdim) {
        const float* ra = rt + base;
        const float* da = decay + base;
        const float* ka = kt + base;
        const float* aa = aarr + base;
        const float* ba = barr + base;
        float vi = vt[base + lane];
        float s0 = 0.f, s1 = 0.f, s2 = 0.f, s3 = 0.f;
        #pragma unroll
        for (int j = 0; j < 64; j += 4) {
            float4 a4 = *(const float4*)(aa + j);
            s0 += S[j + 0] * a4.x;
            s1 += S[j + 1] * a4.y;
            s2 += S[j + 2] * a4.z;
            s3 += S[j + 3] * a4.w;
        }
        float sa = (s0 + s1) + (s2 + s3);
        float o0 = 0.f, o1 = 0.f, o2 = 0.f, o3 = 0.f;
        #pragma unroll
        for (int j = 0; j < 64; j += 4) {
            float4 d4 = *(const float4*)(da + j);
            float4 b4 = *(const float4*)(ba + j);
            float4 k4 = *(const float4*)(ka + j);
            float4 r4 = *(const float4*)(ra + j);
            S[j + 0] = S[j + 0] * d4.x + sa * b4.x + vi * k4.x; o0 += S[j + 0] * r4.x;
            S[j + 1] = S[j + 1] * d4.y + sa * b4.y + vi * k4.y; o1 += S[j + 1] * r4.y;
            S[j + 2] = S[j + 2] * d4.z + sa * b4.z + vi * k4.z; o2 += S[j + 2] * r4.z;
            S[j + 3] = S[j + 3] * d4.w + sa * b4.w + vi * k4.w; o3 += S[j + 3] * r4.w;
        }
        wkvt[base + lane] = (o0 + o1) + (o2 + o3);
    }
}

// ---------------------------------------------------------------------------
// E2: pt = GroupNorm(rt*wkvt)*ln_g + ln_b + ut; gtpt = gt*pt
// ---------------------------------------------------------------------------
__global__ __launch_bounds__(256) void e2_kernel(
    const float* __restrict__ rt, const float* __restrict__ wkvt,
    const float* __restrict__ ut, const float* __restrict__ gt,
    const float* __restrict__ ln_g, const float* __restrict__ ln_b,
    float* __restrict__ gtpt)
{
    int gid = blockIdx.x * 4 + (threadIdx.x >> 6);
    int lane = threadIdx.x & 63;
    int h = gid % Hdim;
    size_t idx = (size_t)gid * 64 + lane;
    int c = h * 64 + lane;
    float x = rt[idx] * wkvt[idx];
    float mu = wsum64(x) * (1.f / 64.f);
    float d = x - mu;
    float var = wsum64(d * d) * (1.f / 64.f);
    float xn = d / sqrtf(var + EPS_GN);
    float pt = xn * ln_g[c] + ln_b[c] + ut[idx];
    gtpt[idx] = gt[idx] * pt;
}

// ---------------------------------------------------------------------------
extern "C" void kernel_launch(void* const* d_in, const int* in_sizes, int n_in,
                              void* d_out, int out_size, void* d_ws, size_t ws_size,
                              hipStream_t stream)
{
    (void)in_sizes; (void)n_in; (void)out_size; (void)ws_size;
    const float* xt      = (const float*)d_in[0];
    const float* v_first = (const float*)d_in[1];
    const float* tmix_r  = (const float*)d_in[2];
    const float* tmix_w  = (const float*)d_in[3];
    const float* tmix_k  = (const float*)d_in[4];
    const float* tmix_v  = (const float*)d_in[5];
    const float* tmix_a  = (const float*)d_in[6];
    const float* tmix_g  = (const float*)d_in[7];
    const float* w1 = (const float*)d_in[8];
    const float* w2 = (const float*)d_in[9];
    const float* w0 = (const float*)d_in[10];
    const float* a1 = (const float*)d_in[11];
    const float* a2 = (const float*)d_in[12];
    const float* a0 = (const float*)d_in[13];
    const float* v1 = (const float*)d_in[14];
    const float* v2 = (const float*)d_in[15];
    const float* v0 = (const float*)d_in[16];
    const float* g1 = (const float*)d_in[17];
    const float* g2 = (const float*)d_in[18];
    const float* k_k = (const float*)d_in[19];
    const float* k_a = (const float*)d_in[20];
    const float* r_k = (const float*)d_in[21];
    const float* W_r = (const float*)d_in[22];
    const float* W_k = (const float*)d_in[23];
    const float* W_v = (const float*)d_in[24];
    const float* W_o = (const float*)d_in[25];
    const float* ln_g = (const float*)d_in[26];
    const float* ln_b = (const float*)d_in[27];

    float* out = (float*)d_out;
    const size_t BTC = (size_t)Bdim * Tdim * Cdim;   // 2,097,152
    const int M = Bdim * Tdim;                        // 2048

    float* ws = (float*)d_ws;
    float* rt    = ws + 0 * BTC;
    float* kt    = ws + 1 * BTC;
    float* vraw  = ws + 2 * BTC;
    float* at    = ws + 3 * BTC;
    float* vt    = ws + 4 * BTC;
    float* decay = ws + 5 * BTC;
    float* gt    = ws + 6 * BTC;
    float* aarr  = ws + 7 * BTC;
    float* barr  = ws + 8 * BTC;
    float* ut    = ws + 9 * BTC;
    float* wkv   = ws + 10 * BTC;
    float* gtpt  = ws + 11 * BTC;
    float* hbuf  = ws + 12 * BTC;                     // up to M*128 floats

    dim3 gg(Cdim / BN, M / BM);   // (16,16)

    // Big projections with fused token-shift lerp
    gemm_btk<<<gg, 256, 0, stream>>>(xt, tmix_r, W_r, rt, M, Cdim, Cdim, Tdim, 1);
    gemm_btk<<<gg, 256, 0, stream>>>(xt, tmix_k, W_k, kt, M, Cdim, Cdim, Tdim, 1);
    gemm_btk<<<gg, 256, 0, stream>>>(xt, tmix_v, W_v, vraw, M, Cdim, Cdim, Tdim, 1);

    // Low-rank: w -> decay
    lr1_kernel<<<M, 256, 0, stream>>>(xt, tmix_w, w1, hbuf, 64, 2, Tdim);
    lr2_kernel<<<dim3(Cdim / 256, M), 256, 0, stream>>>(hbuf, w2, w0, decay, 64, 3);
    // a -> at
    lr1_kernel<<<M, 256, 0, stream>>>(xt, tmix_a, a1, hbuf, 64, 0, Tdim);
    lr2_kernel<<<dim3(Cdim / 256, M), 256, 0, stream>>>(hbuf, a2, a0, at, 64, 1);
    // v -> vt
    lr1_kernel<<<M, 256, 0, stream>>>(xt, tmix_v, v1, hbuf, 32, 0, Tdim);
    lr2_kernel<<<dim3(Cdim / 256, M), 256, 0, stream>>>(hbuf, v2, v0, vt, 32, 1);
    // g -> gt
    lr1_kernel<<<M, 256, 0, stream>>>(xt, tmix_g, g1, hbuf, 128, 1, Tdim);
    lr2_kernel<<<dim3(Cdim / 256, M), 256, 0, stream>>>(hbuf, g2, nullptr, gt, 128, 0);

    // E1: a/b arrays, ut, v_first passthrough
    e1_kernel<<<(Bdim * Tdim * Hdim) / 4, 256, 0, stream>>>(
        kt, at, rt, vraw, vt, v_first, k_k, k_a, r_k,
        aarr, barr, ut, out + BTC);

    // WKV sequential scan
    wkv_kernel<<<Bdim * Hdim, 64, 0, stream>>>(rt, decay, kt, vt, aarr, barr, wkv);

    // E2: groupnorm + ut, gate
    e2_kernel<<<(Bdim * Tdim * Hdim) / 4, 256, 0, stream>>>(
        rt, wkv, ut, gt, ln_g, ln_b, gtpt);

    // Output projection
    gemm_btk<<<gg, 256, 0, stream>>>(gtpt, nullptr, W_o, out, M, Cdim, Cdim, Tdim, 0);
}

// Round 2
// 2352.114 us; speedup vs baseline: 1.8497x; 1.8497x over previous
//
#include <hip/hip_runtime.h>
#include <math.h>

#define Bdim 2
#define Tdim 1024
#define Cdim 1024
#define Hdim 16
#define Ndim 64
#define EPS_GN 0.00064f

static __device__ __forceinline__ float sigf(float x) { return 1.f / (1.f + expf(-x)); }

static __device__ __forceinline__ float wsum64(float v) {
    #pragma unroll
    for (int m = 1; m < 64; m <<= 1) v += __shfl_xor(v, m);
    return v;
}

// ---------------------------------------------------------------------------
// Big GEMM: out[m][n] = sum_k A[m][k] * W[n][k]   (W used transposed)
// Optional fused token-shift lerp on A: A[m][k] = x[m][k] + (x[m-1][k] - x[m][k])*mix[k]
// BM=128, BN=64, BK=16, 256 threads, 8x4 per thread.
// ---------------------------------------------------------------------------
#define BM 128
#define BN 64
#define BK 16

__global__ __launch_bounds__(256) void gemm_btk(
    const float* __restrict__ Asrc, const float* __restrict__ mixv,
    const float* __restrict__ W, float* __restrict__ Cout,
    int M, int N, int K, int Tlen, int lerp)
{
    __shared__ float As[BK][BM];
    __shared__ float Ws[BK][BN];
    int tid = threadIdx.x;
    int bm = blockIdx.y * BM, bn = blockIdx.x * BN;
    int tx = tid & 15, ty = tid >> 4;
    float acc[8][4];
    #pragma unroll
    for (int i = 0; i < 8; ++i)
        #pragma unroll
        for (int j = 0; j < 4; ++j) acc[i][j] = 0.f;

    int lrA = tid >> 1;          // 0..127
    int lkA = (tid & 1) * 8;     // 0 or 8
    int lrW = tid >> 2;          // 0..63
    int lkW = (tid & 3) * 4;     // 0,4,8,12

    for (int k0 = 0; k0 < K; k0 += BK) {
        {   // A tile (optionally lerped)
            int m = bm + lrA;
            const float* p = Asrc + (size_t)m * K + k0 + lkA;
            #pragma unroll
            for (int q = 0; q < 2; ++q) {
                float4 v = *(const float4*)(p + q * 4);
                if (lerp) {
                    int t = m % Tlen;
                    float4 pv = make_float4(0.f, 0.f, 0.f, 0.f);
                    if (t > 0) pv = *(const float4*)(p + q * 4 - K);
                    float4 mv = *(const float4*)(mixv + k0 + lkA + q * 4);
                    v.x += (pv.x - v.x) * mv.x;
                    v.y += (pv.y - v.y) * mv.y;
                    v.z += (pv.z - v.z) * mv.z;
                    v.w += (pv.w - v.w) * mv.w;
                }
                As[lkA + q * 4 + 0][lrA] = v.x;
                As[lkA + q * 4 + 1][lrA] = v.y;
                As[lkA + q * 4 + 2][lrA] = v.z;
                As[lkA + q * 4 + 3][lrA] = v.w;
            }
        }
        {   // W tile
            int n = bn + lrW;
            const float* p = W + (size_t)n * K + k0 + lkW;
            float4 v = *(const float4*)p;
            Ws[lkW + 0][lrW] = v.x; Ws[lkW + 1][lrW] = v.y;
            Ws[lkW + 2][lrW] = v.z; Ws[lkW + 3][lrW] = v.w;
        }
        __syncthreads();
        #pragma unroll
        for (int kk = 0; kk < BK; ++kk) {
            float a8[8], w4[4];
            *(float4*)&a8[0] = *(const float4*)&As[kk][ty * 8];
            *(float4*)&a8[4] = *(const float4*)&As[kk][ty * 8 + 4];
            *(float4*)&w4[0] = *(const float4*)&Ws[kk][tx * 4];
            #pragma unroll
            for (int i = 0; i < 8; ++i)
                #pragma unroll
                for (int j = 0; j < 4; ++j)
                    acc[i][j] += a8[i] * w4[j];
        }
        __syncthreads();
    }
    #pragma unroll
    for (int i = 0; i < 8; ++i) {
        int m = bm + ty * 8 + i;
        #pragma unroll
        for (int j = 0; j < 4; ++j)
            Cout[(size_t)m * N + bn + tx * 4 + j] = acc[i][j];
    }
}

// ---------------------------------------------------------------------------
// Low-rank stage 1: H[m][n] = act( sum_k lerp(x)[m][k] * M1[k][n] ), n < D
// ---------------------------------------------------------------------------
__global__ __launch_bounds__(256) void lr1_kernel(
    const float* __restrict__ X, const float* __restrict__ mixv,
    const float* __restrict__ M1, float* __restrict__ Hout,
    int D, int act, int Tlen)
{
    __shared__ float row[Cdim];
    __shared__ float red[256];
    int m = blockIdx.x;
    int tid = threadIdx.x;
    int t = m % Tlen;
    const float* xr = X + (size_t)m * Cdim;
    #pragma unroll
    for (int q = 0; q < 4; ++q) {
        int kq = tid + q * 256;
        float v = xr[kq];
        float pv = (t > 0) ? xr[kq - Cdim] : 0.f;
        row[kq] = v + (pv - v) * mixv[kq];
    }
    __syncthreads();
    int P = 256 / D;
    int p = tid / D, n = tid % D;
    int klen = Cdim / P;
    float acc = 0.f;
    int kend = (p + 1) * klen;
    for (int k = p * klen; k < kend; ++k)
        acc += row[k] * M1[(size_t)k * D + n];
    red[tid] = acc;
    __syncthreads();
    if (tid < D) {
        float s = 0.f;
        for (int q = 0; q < P; ++q) s += red[tid + q * D];
        if (act == 1) s = sigf(s);
        else if (act == 2) s = tanhf(s);
        Hout[(size_t)m * D + tid] = s;
    }
}

// ---------------------------------------------------------------------------
// Low-rank stage 2: Out[m][n] = act( sum_k H[m][k]*M2[k][n] + bias[n] )
// act: 0 none, 1 sigmoid, 3 sigmoid * e^-0.5
// ---------------------------------------------------------------------------
__global__ __launch_bounds__(256) void lr2_kernel(
    const float* __restrict__ Hin, const float* __restrict__ M2,
    const float* __restrict__ bias, float* __restrict__ Out,
    int D, int act)
{
    __shared__ float hs[128];
    int m = blockIdx.y;
    int n = blockIdx.x * 256 + threadIdx.x;
    if (threadIdx.x < D) hs[threadIdx.x] = Hin[(size_t)m * D + threadIdx.x];
    __syncthreads();
    float acc = bias ? bias[n] : 0.f;
    for (int k = 0; k < D; ++k)
        acc += hs[k] * M2[(size_t)k * Cdim + n];
    if (act == 1) acc = sigf(acc);
    else if (act == 3) acc = sigf(acc) * 0.60653065971263342f;
    Out[(size_t)m * Cdim + n] = acc;
}

// ---------------------------------------------------------------------------
// E1: per (b,t,h) group of 64: kk-normalize -> a=-kkn, b=kkn*at;
//     ut = (sum rt*k*r_k)*vmix; out2 = v_first copy.
// ---------------------------------------------------------------------------
__global__ __launch_bounds__(256) void e1_kernel(
    const float* __restrict__ kt, const float* __restrict__ at,
    const float* __restrict__ rt, const float* __restrict__ vraw,
    const float* __restrict__ vt, const float* __restrict__ vfirst,
    const float* __restrict__ k_k, const float* __restrict__ k_a,
    const float* __restrict__ r_k,
    float* __restrict__ aarr, float* __restrict__ barr,
    float* __restrict__ ut, float* __restrict__ out2)
{
    int gid = blockIdx.x * 4 + (threadIdx.x >> 6);
    int lane = threadIdx.x & 63;
    int h = gid % Hdim;
    size_t idx = (size_t)gid * 64 + lane;
    int c = h * 64 + lane;
    float ktv = kt[idx], atv = at[idx];
    float kk = ktv * k_k[c];
    float ss = wsum64(kk * kk);
    float norm = sqrtf(ss);
    float kkn = kk / fmaxf(norm, 1e-12f);
    aarr[idx] = -kkn;
    barr[idx] = kkn * atv;
    float kmix = ktv * (1.f + (atv - 1.f) * k_a[c]);
    float rv = rt[idx];
    float dot = wsum64(rv * kmix * r_k[c]);
    float vm = vraw[idx];
    float vf = vfirst[idx];
    vm = vm + (vf - vm) * vt[idx];
    ut[idx] = dot * vm;
    out2[idx] = vf;
}

// ---------------------------------------------------------------------------
// WKV scan with global_load_lds ring-buffer pipeline.
// One wave per (b,h). Lane i holds state row S[i][0..63] in regs.
// Ring: 8 step-slots x 6 vectors (r,d,k,a,b,v) x 64 floats = 12 KB LDS.
// Per step: issue 6 async loads for step t+PRE, s_waitcnt vmcnt(6*PRE),
// consume step t's operands via uniform ds_read_b128 broadcast.
// ---------------------------------------------------------------------------
#define WKV_PRE 4
#define WKV_RING 8

static __device__ __forceinline__ void gload_lds4(const float* g, float* l) {
    __builtin_amdgcn_global_load_lds(
        (const __attribute__((address_space(1))) void*)g,
        (__attribute__((address_space(3))) void*)l, 4, 0, 0);
}

__global__ __launch_bounds__(64) void wkv_kernel(
    const float* __restrict__ rt, const float* __restrict__ decay,
    const float* __restrict__ kt, const float* __restrict__ vt,
    const float* __restrict__ aarr, const float* __restrict__ barr,
    float* __restrict__ wkvt)
{
    __shared__ float ring[WKV_RING][6][64];
    int bh = blockIdx.x;
    int b = bh / Hdim, h = bh % Hdim;
    int lane = threadIdx.x;
    float S[64];
    #pragma unroll
    for (int j = 0; j < 64; ++j) S[j] = 0.f;

    const size_t base0 = ((size_t)b * Tdim) * Cdim + (size_t)h * Ndim;

    // prologue: prefetch steps 0..PRE-1
    #pragma unroll
    for (int p = 0; p < WKV_PRE; ++p) {
        size_t gb = base0 + (size_t)p * Cdim;
        int slot = p;
        gload_lds4(rt    + gb + lane, &ring[slot][0][0]);
        gload_lds4(decay + gb + lane, &ring[slot][1][0]);
        gload_lds4(kt    + gb + lane, &ring[slot][2][0]);
        gload_lds4(aarr  + gb + lane, &ring[slot][3][0]);
        gload_lds4(barr  + gb + lane, &ring[slot][4][0]);
        gload_lds4(vt    + gb + lane, &ring[slot][5][0]);
    }

    size_t gbase = base0;
    for (int t = 0; t < Tdim; ++t, gbase += Cdim) {
        // issue prefetch for step t+PRE
        if (t + WKV_PRE < Tdim) {
            size_t gb = base0 + (size_t)(t + WKV_PRE) * Cdim;
            int slot = (t + WKV_PRE) & (WKV_RING - 1);
            gload_lds4(rt    + gb + lane, &ring[slot][0][0]);
            gload_lds4(decay + gb + lane, &ring[slot][1][0]);
            gload_lds4(kt    + gb + lane, &ring[slot][2][0]);
            gload_lds4(aarr  + gb + lane, &ring[slot][3][0]);
            gload_lds4(barr  + gb + lane, &ring[slot][4][0]);
            gload_lds4(vt    + gb + lane, &ring[slot][5][0]);
        }
        // wait until step t's 6 loads have landed (loads retire in order;
        // at most 6*PRE newer loads may remain outstanding)
        asm volatile("s_waitcnt vmcnt(24)" ::: "memory");

        const int slot = t & (WKV_RING - 1);
        const float* Ra = &ring[slot][0][0];
        const float* Da = &ring[slot][1][0];
        const float* Ka = &ring[slot][2][0];
        const float* Aa = &ring[slot][3][0];
        const float* Ba = &ring[slot][4][0];
        float vi = ring[slot][5][lane];

        float s0 = 0.f, s1 = 0.f, s2 = 0.f, s3 = 0.f;
        #pragma unroll
        for (int j = 0; j < 64; j += 4) {
            float4 a4 = *(const float4*)(Aa + j);
            s0 += S[j + 0] * a4.x;
            s1 += S[j + 1] * a4.y;
            s2 += S[j + 2] * a4.z;
            s3 += S[j + 3] * a4.w;
        }
        float sa = (s0 + s1) + (s2 + s3);

        float o0 = 0.f, o1 = 0.f, o2 = 0.f, o3 = 0.f;
        #pragma unroll
        for (int j = 0; j < 64; j += 4) {
            float4 d4 = *(const float4*)(Da + j);
            float4 b4 = *(const float4*)(Ba + j);
            float4 k4 = *(const float4*)(Ka + j);
            float4 r4 = *(const float4*)(Ra + j);
            S[j + 0] = S[j + 0] * d4.x + sa * b4.x + vi * k4.x; o0 += S[j + 0] * r4.x;
            S[j + 1] = S[j + 1] * d4.y + sa * b4.y + vi * k4.y; o1 += S[j + 1] * r4.y;
            S[j + 2] = S[j + 2] * d4.z + sa * b4.z + vi * k4.z; o2 += S[j + 2] * r4.z;
            S[j + 3] = S[j + 3] * d4.w + sa * b4.w + vi * k4.w; o3 += S[j + 3] * r4.w;
        }
        wkvt[gbase + lane] = (o0 + o1) + (o2 + o3);
    }
}

// ---------------------------------------------------------------------------
// E2: pt = GroupNorm(rt*wkvt)*ln_g + ln_b + ut; gtpt = gt*pt
// ---------------------------------------------------------------------------
__global__ __launch_bounds__(256) void e2_kernel(
    const float* __restrict__ rt, const float* __restrict__ wkvt,
    const float* __restrict__ ut, const float* __restrict__ gt,
    const float* __restrict__ ln_g, const float* __restrict__ ln_b,
    float* __restrict__ gtpt)
{
    int gid = blockIdx.x * 4 + (threadIdx.x >> 6);
    int lane = threadIdx.x & 63;
    int h = gid % Hdim;
    size_t idx = (size_t)gid * 64 + lane;
    int c = h * 64 + lane;
    float x = rt[idx] * wkvt[idx];
    float mu = wsum64(x) * (1.f / 64.f);
    float d = x - mu;
    float var = wsum64(d * d) * (1.f / 64.f);
    float xn = d / sqrtf(var + EPS_GN);
    float pt = xn * ln_g[c] + ln_b[c] + ut[idx];
    gtpt[idx] = gt[idx] * pt;
}

// ---------------------------------------------------------------------------
extern "C" void kernel_launch(void* const* d_in, const int* in_sizes, int n_in,
                              void* d_out, int out_size, void* d_ws, size_t ws_size,
                              hipStream_t stream)
{
    (void)in_sizes; (void)n_in; (void)out_size; (void)ws_size;
    const float* xt      = (const float*)d_in[0];
    const float* v_first = (const float*)d_in[1];
    const float* tmix_r  = (const float*)d_in[2];
    const float* tmix_w  = (const float*)d_in[3];
    const float* tmix_k  = (const float*)d_in[4];
    const float* tmix_v  = (const float*)d_in[5];
    const float* tmix_a  = (const float*)d_in[6];
    const float* tmix_g  = (const float*)d_in[7];
    const float* w1 = (const float*)d_in[8];
    const float* w2 = (const float*)d_in[9];
    const float* w0 = (const float*)d_in[10];
    const float* a1 = (const float*)d_in[11];
    const float* a2 = (const float*)d_in[12];
    const float* a0 = (const float*)d_in[13];
    const float* v1 = (const float*)d_in[14];
    const float* v2 = (const float*)d_in[15];
    const float* v0 = (const float*)d_in[16];
    const float* g1 = (const float*)d_in[17];
    const float* g2 = (const float*)d_in[18];
    const float* k_k = (const float*)d_in[19];
    const float* k_a = (const float*)d_in[20];
    const float* r_k = (const float*)d_in[21];
    const float* W_r = (const float*)d_in[22];
    const float* W_k = (const float*)d_in[23];
    const float* W_v = (const float*)d_in[24];
    const float* W_o = (const float*)d_in[25];
    const float* ln_g = (const float*)d_in[26];
    const float* ln_b = (const float*)d_in[27];

    float* out = (float*)d_out;
    const size_t BTC = (size_t)Bdim * Tdim * Cdim;   // 2,097,152
    const int M = Bdim * Tdim;                        // 2048

    float* ws = (float*)d_ws;
    float* rt    = ws + 0 * BTC;
    float* kt    = ws + 1 * BTC;
    float* vraw  = ws + 2 * BTC;
    float* at    = ws + 3 * BTC;
    float* vt    = ws + 4 * BTC;
    float* decay = ws + 5 * BTC;
    float* gt    = ws + 6 * BTC;
    float* aarr  = ws + 7 * BTC;
    float* barr  = ws + 8 * BTC;
    float* ut    = ws + 9 * BTC;
    float* wkv   = ws + 10 * BTC;
    float* gtpt  = ws + 11 * BTC;
    float* hbuf  = ws + 12 * BTC;                     // up to M*128 floats

    dim3 gg(Cdim / BN, M / BM);   // (16,16)

    // Big projections with fused token-shift lerp
    gemm_btk<<<gg, 256, 0, stream>>>(xt, tmix_r, W_r, rt, M, Cdim, Cdim, Tdim, 1);
    gemm_btk<<<gg, 256, 0, stream>>>(xt, tmix_k, W_k, kt, M, Cdim, Cdim, Tdim, 1);
    gemm_btk<<<gg, 256, 0, stream>>>(xt, tmix_v, W_v, vraw, M, Cdim, Cdim, Tdim, 1);

    // Low-rank: w -> decay
    lr1_kernel<<<M, 256, 0, stream>>>(xt, tmix_w, w1, hbuf, 64, 2, Tdim);
    lr2_kernel<<<dim3(Cdim / 256, M), 256, 0, stream>>>(hbuf, w2, w0, decay, 64, 3);
    // a -> at
    lr1_kernel<<<M, 256, 0, stream>>>(xt, tmix_a, a1, hbuf, 64, 0, Tdim);
    lr2_kernel<<<dim3(Cdim / 256, M), 256, 0, stream>>>(hbuf, a2, a0, at, 64, 1);
    // v -> vt
    lr1_kernel<<<M, 256, 0, stream>>>(xt, tmix_v, v1, hbuf, 32, 0, Tdim);
    lr2_kernel<<<dim3(Cdim / 256, M), 256, 0, stream>>>(hbuf, v2, v0, vt, 32, 1);
    // g -> gt
    lr1_kernel<<<M, 256, 0, stream>>>(xt, tmix_g, g1, hbuf, 128, 1, Tdim);
    lr2_kernel<<<dim3(Cdim / 256, M), 256, 0, stream>>>(hbuf, g2, nullptr, gt, 128, 0);

    // E1: a/b arrays, ut, v_first passthrough
    e1_kernel<<<(Bdim * Tdim * Hdim) / 4, 256, 0, stream>>>(
        kt, at, rt, vraw, vt, v_first, k_k, k_a, r_k,
        aarr, barr, ut, out + BTC);

    // WKV sequential scan (pipelined)
    wkv_kernel<<<Bdim * Hdim, 64, 0, stream>>>(rt, decay, kt, vt, aarr, barr, wkv);

    // E2: groupnorm + ut, gate
    e2_kernel<<<(Bdim * Tdim * Hdim) / 4, 256, 0, stream>>>(
        rt, wkv, ut, gt, ln_g, ln_b, gtpt);

    // Output projection
    gemm_btk<<<gg, 256, 0, stream>>>(gtpt, nullptr, W_o, out, M, Cdim, Cdim, Tdim, 0);
}

// Round 3
// 1558.732 us; speedup vs baseline: 2.7912x; 1.5090x over previous
//
#include <hip/hip_runtime.h>
#include <math.h>

#define Bdim 2
#define Tdim 1024
#define Cdim 1024
#define Hdim 16
#define Ndim 64
#define EPS_GN 0.00064f

static __device__ __forceinline__ float sigf(float x) { return 1.f / (1.f + expf(-x)); }

static __device__ __forceinline__ float wsum64(float v) {
    #pragma unroll
    for (int m = 1; m < 64; m <<= 1) v += __shfl_xor(v, m);
    return v;
}

// ---------------------------------------------------------------------------
// Big GEMM: out[m][n] = sum_k A[m][k] * W[n][k]   (W used transposed)
// Optional fused token-shift lerp on A.
// ---------------------------------------------------------------------------
#define BM 128
#define BN 64
#define BK 16

__global__ __launch_bounds__(256) void gemm_btk(
    const float* __restrict__ Asrc, const float* __restrict__ mixv,
    const float* __restrict__ W, float* __restrict__ Cout,
    int M, int N, int K, int Tlen, int lerp)
{
    __shared__ float As[BK][BM];
    __shared__ float Ws[BK][BN];
    int tid = threadIdx.x;
    int bm = blockIdx.y * BM, bn = blockIdx.x * BN;
    int tx = tid & 15, ty = tid >> 4;
    float acc[8][4];
    #pragma unroll
    for (int i = 0; i < 8; ++i)
        #pragma unroll
        for (int j = 0; j < 4; ++j) acc[i][j] = 0.f;

    int lrA = tid >> 1;
    int lkA = (tid & 1) * 8;
    int lrW = tid >> 2;
    int lkW = (tid & 3) * 4;

    for (int k0 = 0; k0 < K; k0 += BK) {
        {
            int m = bm + lrA;
            const float* p = Asrc + (size_t)m * K + k0 + lkA;
            #pragma unroll
            for (int q = 0; q < 2; ++q) {
                float4 v = *(const float4*)(p + q * 4);
                if (lerp) {
                    int t = m % Tlen;
                    float4 pv = make_float4(0.f, 0.f, 0.f, 0.f);
                    if (t > 0) pv = *(const float4*)(p + q * 4 - K);
                    float4 mv = *(const float4*)(mixv + k0 + lkA + q * 4);
                    v.x += (pv.x - v.x) * mv.x;
                    v.y += (pv.y - v.y) * mv.y;
                    v.z += (pv.z - v.z) * mv.z;
                    v.w += (pv.w - v.w) * mv.w;
                }
                As[lkA + q * 4 + 0][lrA] = v.x;
                As[lkA + q * 4 + 1][lrA] = v.y;
                As[lkA + q * 4 + 2][lrA] = v.z;
                As[lkA + q * 4 + 3][lrA] = v.w;
            }
        }
        {
            int n = bn + lrW;
            const float* p = W + (size_t)n * K + k0 + lkW;
            float4 v = *(const float4*)p;
            Ws[lkW + 0][lrW] = v.x; Ws[lkW + 1][lrW] = v.y;
            Ws[lkW + 2][lrW] = v.z; Ws[lkW + 3][lrW] = v.w;
        }
        __syncthreads();
        #pragma unroll
        for (int kk = 0; kk < BK; ++kk) {
            float a8[8], w4[4];
            *(float4*)&a8[0] = *(const float4*)&As[kk][ty * 8];
            *(float4*)&a8[4] = *(const float4*)&As[kk][ty * 8 + 4];
            *(float4*)&w4[0] = *(const float4*)&Ws[kk][tx * 4];
            #pragma unroll
            for (int i = 0; i < 8; ++i)
                #pragma unroll
                for (int j = 0; j < 4; ++j)
                    acc[i][j] += a8[i] * w4[j];
        }
        __syncthreads();
    }
    #pragma unroll
    for (int i = 0; i < 8; ++i) {
        int m = bm + ty * 8 + i;
        #pragma unroll
        for (int j = 0; j < 4; ++j)
            Cout[(size_t)m * N + bn + tx * 4 + j] = acc[i][j];
    }
}

// ---------------------------------------------------------------------------
// Low-rank stage 1
// ---------------------------------------------------------------------------
__global__ __launch_bounds__(256) void lr1_kernel(
    const float* __restrict__ X, const float* __restrict__ mixv,
    const float* __restrict__ M1, float* __restrict__ Hout,
    int D, int act, int Tlen)
{
    __shared__ float row[Cdim];
    __shared__ float red[256];
    int m = blockIdx.x;
    int tid = threadIdx.x;
    int t = m % Tlen;
    const float* xr = X + (size_t)m * Cdim;
    #pragma unroll
    for (int q = 0; q < 4; ++q) {
        int kq = tid + q * 256;
        float v = xr[kq];
        float pv = (t > 0) ? xr[kq - Cdim] : 0.f;
        row[kq] = v + (pv - v) * mixv[kq];
    }
    __syncthreads();
    int P = 256 / D;
    int p = tid / D, n = tid % D;
    int klen = Cdim / P;
    float acc = 0.f;
    int kend = (p + 1) * klen;
    for (int k = p * klen; k < kend; ++k)
        acc += row[k] * M1[(size_t)k * D + n];
    red[tid] = acc;
    __syncthreads();
    if (tid < D) {
        float s = 0.f;
        for (int q = 0; q < P; ++q) s += red[tid + q * D];
        if (act == 1) s = sigf(s);
        else if (act == 2) s = tanhf(s);
        Hout[(size_t)m * D + tid] = s;
    }
}

// ---------------------------------------------------------------------------
// Low-rank stage 2. act: 0 none, 1 sigmoid, 3 sigmoid * e^-0.5
// ---------------------------------------------------------------------------
__global__ __launch_bounds__(256) void lr2_kernel(
    const float* __restrict__ Hin, const float* __restrict__ M2,
    const float* __restrict__ bias, float* __restrict__ Out,
    int D, int act)
{
    __shared__ float hs[128];
    int m = blockIdx.y;
    int n = blockIdx.x * 256 + threadIdx.x;
    if (threadIdx.x < D) hs[threadIdx.x] = Hin[(size_t)m * D + threadIdx.x];
    __syncthreads();
    float acc = bias ? bias[n] : 0.f;
    for (int k = 0; k < D; ++k)
        acc += hs[k] * M2[(size_t)k * Cdim + n];
    if (act == 1) acc = sigf(acc);
    else if (act == 3) acc = sigf(acc) * 0.60653065971263342f;
    Out[(size_t)m * Cdim + n] = acc;
}

// ---------------------------------------------------------------------------
// E1
// ---------------------------------------------------------------------------
__global__ __launch_bounds__(256) void e1_kernel(
    const float* __restrict__ kt, const float* __restrict__ at,
    const float* __restrict__ rt, const float* __restrict__ vraw,
    const float* __restrict__ vt, const float* __restrict__ vfirst,
    const float* __restrict__ k_k, const float* __restrict__ k_a,
    const float* __restrict__ r_k,
    float* __restrict__ aarr, float* __restrict__ barr,
    float* __restrict__ ut, float* __restrict__ out2)
{
    int gid = blockIdx.x * 4 + (threadIdx.x >> 6);
    int lane = threadIdx.x & 63;
    int h = gid % Hdim;
    size_t idx = (size_t)gid * 64 + lane;
    int c = h * 64 + lane;
    float ktv = kt[idx], atv = at[idx];
    float kk = ktv * k_k[c];
    float ss = wsum64(kk * kk);
    float norm = sqrtf(ss);
    float kkn = kk / fmaxf(norm, 1e-12f);
    aarr[idx] = -kkn;
    barr[idx] = kkn * atv;
    float kmix = ktv * (1.f + (atv - 1.f) * k_a[c]);
    float rv = rt[idx];
    float dot = wsum64(rv * kmix * r_k[c]);
    float vm = vraw[idx];
    float vf = vfirst[idx];
    vm = vm + (vf - vm) * vt[idx];
    ut[idx] = dot * vm;
    out2[idx] = vf;
}

// ---------------------------------------------------------------------------
// WKV scan, 4-way row-split + 2 (b,h) groups per 512-thread block.
// Group g (waves 4g..4g+3) handles bh = blockIdx*2+g.
// Within a group: lane = i_loc*4 + q; wave w owns rows i = w*16 + i_loc;
// lane owns columns j in [16q, 16q+16). sa/out reduced via shfl_xor 1,2.
// Staging: wave w<3 loads vectors {2w, 2w+1} for step t+PRE via
// global_load_lds; counted s_waitcnt vmcnt(8) (never drained) + raw
// s_barrier per step.  Ring: 2 groups x 8 slots x 6 vec x 64 f = 24 KB.
// ---------------------------------------------------------------------------
#define WKV_PRE 4
#define WKV_RING 8
#define GPW 2

static __device__ __forceinline__ void gload_lds4(const float* g, float* l) {
    __builtin_amdgcn_global_load_lds(
        (const __attribute__((address_space(1))) void*)g,
        (__attribute__((address_space(3))) void*)l, 4, 0, 0);
}

__global__ __launch_bounds__(512) void wkv_kernel(
    const float* __restrict__ rt, const float* __restrict__ decay,
    const float* __restrict__ kt, const float* __restrict__ vt,
    const float* __restrict__ aarr, const float* __restrict__ barr,
    float* __restrict__ wkvt)
{
    __shared__ float ring[GPW][WKV_RING][6][64];
    int tid = threadIdx.x;
    int wave = tid >> 6, lane = tid & 63;
    int g = wave >> 2, w = wave & 3;
    int bh = blockIdx.x * GPW + g;
    int b = bh / Hdim, h = bh % Hdim;
    int i_loc = lane >> 2, q = lane & 3;
    int i = w * 16 + i_loc;     // value row owned (16 per wave)
    int jb = q * 16;            // column slice [jb, jb+16)

    // vector order in ring: 0=r 1=d 2=k 3=a 4=b 5=v
    const float* src0 = rt;  const float* src1 = decay;
    int v0 = 0;
    if (w == 1) { src0 = kt;   src1 = aarr; v0 = 2; }
    if (w == 2) { src0 = barr; src1 = vt;   v0 = 4; }

    float S[16];
    #pragma unroll
    for (int jj = 0; jj < 16; ++jj) S[jj] = 0.f;

    const size_t base0 = ((size_t)b * Tdim) * Cdim + (size_t)h * Ndim;

    if (w < 3) {
        #pragma unroll
        for (int p = 0; p < WKV_PRE; ++p) {
            size_t gb = base0 + (size_t)p * Cdim;
            gload_lds4(src0 + gb + lane, &ring[g][p][v0][0]);
            gload_lds4(src1 + gb + lane, &ring[g][p][v0 + 1][0]);
        }
    }
    // one-time drain so per-step counted waits are exact from t=0
    asm volatile("s_waitcnt vmcnt(0)" ::: "memory");

    size_t gbase = base0;
    for (int t = 0; t < Tdim; ++t, gbase += Cdim) {
        if (w < 3 && t + WKV_PRE < Tdim) {
            size_t gb = base0 + (size_t)(t + WKV_PRE) * Cdim;
            int slot = (t + WKV_PRE) & (WKV_RING - 1);
            gload_lds4(src0 + gb + lane, &ring[g][slot][v0][0]);
            gload_lds4(src1 + gb + lane, &ring[g][slot][v0 + 1][0]);
        }
        // newest 8 vmem ops after step-t's load pair: 4 loads-pairs + 4 stores
        asm volatile("s_waitcnt vmcnt(8)" ::: "memory");
        __builtin_amdgcn_s_barrier();
        __builtin_amdgcn_sched_barrier(0);

        const int slot = t & (WKV_RING - 1);
        const float* Ra = &ring[g][slot][0][jb];
        const float* Da = &ring[g][slot][1][jb];
        const float* Ka = &ring[g][slot][2][jb];
        const float* Aa = &ring[g][slot][3][jb];
        const float* Ba = &ring[g][slot][4][jb];
        float vi = ring[g][slot][5][i];

        float av[16], dv[16], bv[16], kv[16], rv[16];
        #pragma unroll
        for (int c4 = 0; c4 < 4; ++c4) {
            *(float4*)&av[c4 * 4] = *(const float4*)(Aa + c4 * 4);
            *(float4*)&dv[c4 * 4] = *(const float4*)(Da + c4 * 4);
            *(float4*)&bv[c4 * 4] = *(const float4*)(Ba + c4 * 4);
            *(float4*)&kv[c4 * 4] = *(const float4*)(Ka + c4 * 4);
            *(float4*)&rv[c4 * 4] = *(const float4*)(Ra + c4 * 4);
        }

        float sp = 0.f;
        #pragma unroll
        for (int jj = 0; jj < 16; ++jj) sp += S[jj] * av[jj];
        sp += __shfl_xor(sp, 1);
        sp += __shfl_xor(sp, 2);

        float op = 0.f;
        #pragma unroll
        for (int jj = 0; jj < 16; ++jj) {
            S[jj] = S[jj] * dv[jj] + (sp * bv[jj] + vi * kv[jj]);
            op += S[jj] * rv[jj];
        }
        op += __shfl_xor(op, 1);
        op += __shfl_xor(op, 2);
        if (q == 0) wkvt[gbase + i] = op;
    }
}

// ---------------------------------------------------------------------------
// E2
// ---------------------------------------------------------------------------
__global__ __launch_bounds__(256) void e2_kernel(
    const float* __restrict__ rt, const float* __restrict__ wkvt,
    const float* __restrict__ ut, const float* __restrict__ gt,
    const float* __restrict__ ln_g, const float* __restrict__ ln_b,
    float* __restrict__ gtpt)
{
    int gid = blockIdx.x * 4 + (threadIdx.x >> 6);
    int lane = threadIdx.x & 63;
    int h = gid % Hdim;
    size_t idx = (size_t)gid * 64 + lane;
    int c = h * 64 + lane;
    float x = rt[idx] * wkvt[idx];
    float mu = wsum64(x) * (1.f / 64.f);
    float d = x - mu;
    float var = wsum64(d * d) * (1.f / 64.f);
    float xn = d / sqrtf(var + EPS_GN);
    float pt = xn * ln_g[c] + ln_b[c] + ut[idx];
    gtpt[idx] = gt[idx] * pt;
}

// ---------------------------------------------------------------------------
extern "C" void kernel_launch(void* const* d_in, const int* in_sizes, int n_in,
                              void* d_out, int out_size, void* d_ws, size_t ws_size,
                              hipStream_t stream)
{
    (void)in_sizes; (void)n_in; (void)out_size; (void)ws_size;
    const float* xt      = (const float*)d_in[0];
    const float* v_first = (const float*)d_in[1];
    const float* tmix_r  = (const float*)d_in[2];
    const float* tmix_w  = (const float*)d_in[3];
    const float* tmix_k  = (const float*)d_in[4];
    const float* tmix_v  = (const float*)d_in[5];
    const float* tmix_a  = (const float*)d_in[6];
    const float* tmix_g  = (const float*)d_in[7];
    const float* w1 = (const float*)d_in[8];
    const float* w2 = (const float*)d_in[9];
    const float* w0 = (const float*)d_in[10];
    const float* a1 = (const float*)d_in[11];
    const float* a2 = (const float*)d_in[12];
    const float* a0 = (const float*)d_in[13];
    const float* v1 = (const float*)d_in[14];
    const float* v2 = (const float*)d_in[15];
    const float* v0 = (const float*)d_in[16];
    const float* g1 = (const float*)d_in[17];
    const float* g2 = (const float*)d_in[18];
    const float* k_k = (const float*)d_in[19];
    const float* k_a = (const float*)d_in[20];
    const float* r_k = (const float*)d_in[21];
    const float* W_r = (const float*)d_in[22];
    const float* W_k = (const float*)d_in[23];
    const float* W_v = (const float*)d_in[24];
    const float* W_o = (const float*)d_in[25];
    const float* ln_g = (const float*)d_in[26];
    const float* ln_b = (const float*)d_in[27];

    float* out = (float*)d_out;
    const size_t BTC = (size_t)Bdim * Tdim * Cdim;
    const int M = Bdim * Tdim;

    float* ws = (float*)d_ws;
    float* rt    = ws + 0 * BTC;
    float* kt    = ws + 1 * BTC;
    float* vraw  = ws + 2 * BTC;
    float* at    = ws + 3 * BTC;
    float* vt    = ws + 4 * BTC;
    float* decay = ws + 5 * BTC;
    float* gt    = ws + 6 * BTC;
    float* aarr  = ws + 7 * BTC;
    float* barr  = ws + 8 * BTC;
    float* ut    = ws + 9 * BTC;
    float* wkv   = ws + 10 * BTC;
    float* gtpt  = ws + 11 * BTC;
    float* hbuf  = ws + 12 * BTC;

    dim3 gg(Cdim / BN, M / BM);

    gemm_btk<<<gg, 256, 0, stream>>>(xt, tmix_r, W_r, rt, M, Cdim, Cdim, Tdim, 1);
    gemm_btk<<<gg, 256, 0, stream>>>(xt, tmix_k, W_k, kt, M, Cdim, Cdim, Tdim, 1);
    gemm_btk<<<gg, 256, 0, stream>>>(xt, tmix_v, W_v, vraw, M, Cdim, Cdim, Tdim, 1);

    lr1_kernel<<<M, 256, 0, stream>>>(xt, tmix_w, w1, hbuf, 64, 2, Tdim);
    lr2_kernel<<<dim3(Cdim / 256, M), 256, 0, stream>>>(hbuf, w2, w0, decay, 64, 3);
    lr1_kernel<<<M, 256, 0, stream>>>(xt, tmix_a, a1, hbuf, 64, 0, Tdim);
    lr2_kernel<<<dim3(Cdim / 256, M), 256, 0, stream>>>(hbuf, a2, a0, at, 64, 1);
    lr1_kernel<<<M, 256, 0, stream>>>(xt, tmix_v, v1, hbuf, 32, 0, Tdim);
    lr2_kernel<<<dim3(Cdim / 256, M), 256, 0, stream>>>(hbuf, v2, v0, vt, 32, 1);
    lr1_kernel<<<M, 256, 0, stream>>>(xt, tmix_g, g1, hbuf, 128, 1, Tdim);
    lr2_kernel<<<dim3(Cdim / 256, M), 256, 0, stream>>>(hbuf, g2, nullptr, gt, 128, 0);

    e1_kernel<<<(Bdim * Tdim * Hdim) / 4, 256, 0, stream>>>(
        kt, at, rt, vraw, vt, v_first, k_k, k_a, r_k,
        aarr, barr, ut, out + BTC);

    wkv_kernel<<<(Bdim * Hdim) / GPW, 512, 0, stream>>>(rt, decay, kt, vt, aarr, barr, wkv);

    e2_kernel<<<(Bdim * Tdim * Hdim) / 4, 256, 0, stream>>>(
        rt, wkv, ut, gt, ln_g, ln_b, gtpt);

    gemm_btk<<<gg, 256, 0, stream>>>(gtpt, nullptr, W_o, out, M, Cdim, Cdim, Tdim, 0);
}